// Round 2
// baseline (1001.218 us; speedup 1.0000x reference)
//
#include <hip/hip_runtime.h>

#define E_DIM 256
#define HW    1024      // 32*32
#define NQ    32768     // 32*32*32
#define KALL  2048
#define KT    32
#define KSPL  8
#define KSLEN (KALL / KSPL)   // 256

// ws layout:
//   [0, 8KB)             : float csq[2048]
//   [16KB, 16KB+1MB)     : float pvals[8][32768]
//   [16KB+1MB, +1MB)     : int   pidx [8][32768]

__global__ __launch_bounds__(256)
void vq_csq_kernel(const float* __restrict__ cb, float* __restrict__ csq) {
    int k = blockIdx.x * blockDim.x + threadIdx.x;
    if (k >= KALL) return;
    const float4* row = (const float4*)(cb + (size_t)k * E_DIM);
    double s = 0.0;
    #pragma unroll
    for (int i = 0; i < E_DIM / 4; ++i) {
        float4 v = row[i];
        s += (double)v.x * (double)v.x;
        s += (double)v.y * (double)v.y;
        s += (double)v.z * (double)v.z;
        s += (double)v.w * (double)v.w;
    }
    csq[k] = (float)s;   // correctly-rounded fp32 ||c||^2
}

__global__ __launch_bounds__(256, 2)
void vq_argmin_kernel(const float* __restrict__ emb,
                      const float* __restrict__ cb,
                      const float* __restrict__ csq,
                      float* __restrict__ pvals,
                      int* __restrict__ pidx) {
    __shared__ float clds[KT][E_DIM];   // 32 KB

    const int t  = threadIdx.x;
    const int qb = blockIdx.x / KSPL;   // 0..63 : tile of 512 queries
    const int ks = blockIdx.x % KSPL;   // 0..7  : slice of 256 codes

    const int n0  = qb * 512 + t;       // query A
    const int n1  = n0 + 256;           // query B (same image b: hw0 < 768 always)
    const int b   = n0 >> 10;
    const int hw0 = n0 & 1023;
    const int hw1 = hw0 + 256;
    const float* __restrict__ embB = emb + (size_t)b * E_DIM * HW;

    double xsq0 = 0.0, xsq1 = 0.0;      // exact ||x||^2 (binade-accurate is enough)
    float  bestv0 = 1e30f, bestv1 = 1e30f;
    int    besti0 = 0,     besti1 = 0;

    for (int kt = 0; kt < KSLEN / KT; ++kt) {
        const int kbase = ks * KSLEN + kt * KT;

        __syncthreads();   // protect LDS reuse across iterations
        {
            const float4* __restrict__ src = (const float4*)(cb + (size_t)kbase * E_DIM);
            float4* dst = (float4*)&clds[0][0];
            #pragma unroll
            for (int i = 0; i < (KT * E_DIM / 4) / 256; ++i)
                dst[i * 256 + t] = src[i * 256 + t];
        }
        __syncthreads();

        double acc0[KT], acc1[KT];
        #pragma unroll
        for (int k = 0; k < KT; ++k) { acc0[k] = 0.0; acc1[k] = 0.0; }

        for (int e0 = 0; e0 < E_DIM; e0 += 4) {
            const float* __restrict__ pe = embB + (size_t)e0 * HW;
            float a0 = pe[hw0];
            float a1 = pe[HW + hw0];
            float a2 = pe[2 * HW + hw0];
            float a3 = pe[3 * HW + hw0];
            float g0 = pe[hw1];
            float g1 = pe[HW + hw1];
            float g2 = pe[2 * HW + hw1];
            float g3 = pe[3 * HW + hw1];
            double da0 = (double)a0, da1 = (double)a1, da2 = (double)a2, da3 = (double)a3;
            double db0 = (double)g0, db1 = (double)g1, db2 = (double)g2, db3 = (double)g3;
            if (kt == 0) {   // accumulate ||x||^2 once (uniform branch)
                xsq0 = fma(da0, da0, xsq0); xsq0 = fma(da1, da1, xsq0);
                xsq0 = fma(da2, da2, xsq0); xsq0 = fma(da3, da3, xsq0);
                xsq1 = fma(db0, db0, xsq1); xsq1 = fma(db1, db1, xsq1);
                xsq1 = fma(db2, db2, xsq1); xsq1 = fma(db3, db3, xsq1);
            }
            #pragma unroll
            for (int k = 0; k < KT; ++k) {
                float4 c4 = *(const float4*)&clds[k][e0];
                double c0 = (double)c4.x, c1 = (double)c4.y;
                double c2 = (double)c4.z, c3 = (double)c4.w;
                acc0[k] = fma(da0, c0, acc0[k]);
                acc0[k] = fma(da1, c1, acc0[k]);
                acc0[k] = fma(da2, c2, acc0[k]);
                acc0[k] = fma(da3, c3, acc0[k]);
                acc1[k] = fma(db0, c0, acc1[k]);
                acc1[k] = fma(db1, c1, acc1[k]);
                acc1[k] = fma(db2, c2, acc1[k]);
                acc1[k] = fma(db3, c3, acc1[k]);
            }
        }

        // fp32 rounding replay of: d = (x_sq - 2*(x.c)) + c_sq
        float xs0 = (float)xsq0;
        float xs1 = (float)xsq1;
        #pragma unroll
        for (int k = 0; k < KT; ++k) {
            float cs = csq[kbase + k];
            float ga = (float)acc0[k];          // correctly-rounded fp32 dot
            float gb = (float)acc1[k];
            float Ga = ga + ga;                 // exact 2*g
            float Gb = gb + gb;
            float t0 = xs0 - Ga;                // fp32 round (ulp(~256) grid)
            float t1 = xs1 - Gb;
            float d0 = t0 + cs;                 // fp32 round
            float d1 = t1 + cs;
            if (d0 < bestv0) { bestv0 = d0; besti0 = kbase + k; }
            if (d1 < bestv1) { bestv1 = d1; besti1 = kbase + k; }
        }
    }

    pvals[(size_t)ks * NQ + n0] = bestv0;
    pvals[(size_t)ks * NQ + n1] = bestv1;
    pidx [(size_t)ks * NQ + n0] = besti0;
    pidx [(size_t)ks * NQ + n1] = besti1;
}

__global__ __launch_bounds__(256)
void vq_gather_kernel(const float* __restrict__ cb,
                      const float* __restrict__ pvals,
                      const int* __restrict__ pidx,
                      float* __restrict__ out) {
    const int t  = threadIdx.x;
    const int b  = blockIdx.x >> 2;
    const int hq = blockIdx.x & 3;
    const int n  = b * HW + hq * 256 + t;

    float bv = pvals[n];
    int   bi = pidx[n];
    #pragma unroll
    for (int s = 1; s < KSPL; ++s) {
        float v = pvals[(size_t)s * NQ + n];
        int   i = pidx [(size_t)s * NQ + n];
        if (v < bv) { bv = v; bi = i; }   // ascending s + strict < = first-index tiebreak
    }

    const float4* __restrict__ row = (const float4*)(cb + (size_t)bi * E_DIM);
    float* __restrict__ outB = out + (size_t)b * E_DIM * HW + hq * 256 + t;
    #pragma unroll 4
    for (int e4 = 0; e4 < E_DIM / 4; ++e4) {
        float4 c = row[e4];
        outB[(size_t)(e4 * 4 + 0) * HW] = c.x;
        outB[(size_t)(e4 * 4 + 1) * HW] = c.y;
        outB[(size_t)(e4 * 4 + 2) * HW] = c.z;
        outB[(size_t)(e4 * 4 + 3) * HW] = c.w;
    }
}

extern "C" void kernel_launch(void* const* d_in, const int* in_sizes, int n_in,
                              void* d_out, int out_size, void* d_ws, size_t ws_size,
                              hipStream_t stream) {
    const float* emb = (const float*)d_in[0];   // [32, 256, 32, 32] fp32
    const float* cb  = (const float*)d_in[1];   // [2048, 256] fp32
    float* out = (float*)d_out;                 // [32, 256, 32, 32] fp32

    char* ws = (char*)d_ws;
    float* csq   = (float*)ws;
    float* pvals = (float*)(ws + (16 << 10));
    int*   pidx  = (int*)  (ws + (16 << 10) + (1 << 20));

    vq_csq_kernel   <<<KALL / 256, 256, 0, stream>>>(cb, csq);
    vq_argmin_kernel<<<64 * KSPL, 256, 0, stream>>>(emb, cb, csq, pvals, pidx);
    vq_gather_kernel<<<32 * 4, 256, 0, stream>>>(cb, pvals, pidx, out);
}

// Round 3
// 424.435 us; speedup vs baseline: 2.3589x; 2.3589x over previous
//
#include <hip/hip_runtime.h>

typedef unsigned int uint;
typedef unsigned short ushort;
typedef __attribute__((ext_vector_type(8))) short short8v;   // 8 bf16 in 4 VGPRs
typedef __attribute__((ext_vector_type(4))) float float4v;

#define NQ    32768
#define KALL  2048
#define E_DIM 256
#define HW    1024
#define TAU   2.3e-4f

static __device__ __forceinline__ ushort f2bf(float f) {
    uint u = __float_as_uint(f);
    uint r = (u + 0x7fffu + ((u >> 16) & 1u)) >> 16;   // RNE, no NaN inputs
    return (ushort)r;
}

// ---------------- prep: codebook -> bf16 + fp32 csq ----------------
__global__ __launch_bounds__(256)
void prep_cb(const float* __restrict__ cb, ushort* __restrict__ cb1,
             float* __restrict__ csq) {
    int row  = blockIdx.x * 4 + (threadIdx.x >> 6);
    int lane = threadIdx.x & 63;
    float4 v = ((const float4*)cb)[row * 64 + lane];
    double s = (double)v.x * v.x + (double)v.y * v.y +
               (double)v.z * v.z + (double)v.w * v.w;
    for (int m = 1; m < 64; m <<= 1) s += __shfl_xor(s, m);
    if (lane == 0) csq[row] = (float)s;    // fl32(exact ||c||^2)
    uint u0 = (uint)f2bf(v.x) | ((uint)f2bf(v.y) << 16);
    uint u1 = (uint)f2bf(v.z) | ((uint)f2bf(v.w) << 16);
    ((uint2*)cb1)[row * 64 + lane] = make_uint2(u0, u1);
}

// ---------------- prep: emb [B][E][HW] -> xb bf16 [N][E] ----------------
__global__ __launch_bounds__(256)
void prep_x(const float* __restrict__ emb, ushort* __restrict__ xb) {
    __shared__ float ldsf[64 * 65];
    int blk = blockIdx.x;
    int img = blk >> 6;
    int tile = blk & 63;
    int e0  = (tile >> 4) * 64;
    int hw0 = (tile & 15) * 64;
    int t = threadIdx.x;
    int rr = t >> 6;          // 0..3
    int c  = t & 63;
    #pragma unroll 4
    for (int i = 0; i < 16; ++i) {
        int r = i * 4 + rr;
        float v = emb[((img * 256 + e0 + r) << 10) + hw0 + c];
        ldsf[c * 65 + r] = v;              // transpose into LDS, conflict-free
    }
    __syncthreads();
    int hr = t >> 5;          // 0..7
    int ep = t & 31;
    #pragma unroll 4
    for (int i = 0; i < 8; ++i) {
        int hwr = i * 8 + hr;
        float v0 = ldsf[hwr * 65 + ep * 2];
        float v1 = ldsf[hwr * 65 + ep * 2 + 1];
        uint u = (uint)f2bf(v0) | ((uint)f2bf(v1) << 16);
        ((uint*)xb)[((img * 1024 + hw0 + hwr) << 7) + (e0 >> 1) + ep] = u;
    }
}

// ---------------- stage 1: bf16 MFMA GEMM + per-tile top2 ----------------
__global__ __launch_bounds__(256, 2)
void vq_gemm(const ushort* __restrict__ xb, const ushort* __restrict__ cb1,
             const float* __restrict__ csq,
             float* __restrict__ pm1, float* __restrict__ pm2,
             uint* __restrict__ pidxg) {
    __shared__ char smem[50688];          // union: staging (16KB) / entries (49.5KB)
    __shared__ float csq_lds[128];
    char* Asm = smem;
    char* Bsm = smem + 8192;
    float* emin1 = (float*)smem;                 // [128][33]
    float* emin2 = (float*)(smem + 16896);
    uint*  eidx  = (uint*)(smem + 33792);

    int t = threadIdx.x;
    int bi = blockIdx.x;
    int mt = bi >> 4;            // 256 M-tiles
    int nt = bi & 15;            // 16 N-tiles
    int qbase = mt * 128;
    int cbase = nt * 128;

    if (t < 128) csq_lds[t] = csq[cbase + t];

    int wid = t >> 6, lane = t & 63;
    int wr = wid >> 1, wc = wid & 1;
    int lr = lane & 15, lk = lane >> 4;

    float4v acc[4][4];
    #pragma unroll
    for (int i = 0; i < 4; ++i)
        #pragma unroll
        for (int j = 0; j < 4; ++j)
            acc[i][j] = (float4v){0.f, 0.f, 0.f, 0.f};

    // staging map: thread covers rows r0=t>>2 and r1=64+(t>>2), k-chunk kc=t&3
    int r0 = t >> 2, r1 = 64 + (t >> 2), kc = t & 3;
    int dst0 = r0 * 64 + ((kc ^ ((r0 >> 1) & 3)) << 4);   // XOR slot swizzle
    int dst1 = r1 * 64 + ((kc ^ ((r1 >> 1) & 3)) << 4);

    short8v ra0, ra1, rb0, rb1;
    {
        int k0 = 0;
        ra0 = *(const short8v*)(xb  + (size_t)(qbase + r0) * 256 + k0 + kc * 8);
        ra1 = *(const short8v*)(xb  + (size_t)(qbase + r1) * 256 + k0 + kc * 8);
        rb0 = *(const short8v*)(cb1 + (size_t)(cbase + r0) * 256 + k0 + kc * 8);
        rb1 = *(const short8v*)(cb1 + (size_t)(cbase + r1) * 256 + k0 + kc * 8);
    }

    for (int kt = 0; kt < 8; ++kt) {
        __syncthreads();
        *(short8v*)(Asm + dst0) = ra0;
        *(short8v*)(Asm + dst1) = ra1;
        *(short8v*)(Bsm + dst0) = rb0;
        *(short8v*)(Bsm + dst1) = rb1;
        if (kt < 7) {                       // prefetch next K-step under compute
            int k0 = (kt + 1) * 32;
            ra0 = *(const short8v*)(xb  + (size_t)(qbase + r0) * 256 + k0 + kc * 8);
            ra1 = *(const short8v*)(xb  + (size_t)(qbase + r1) * 256 + k0 + kc * 8);
            rb0 = *(const short8v*)(cb1 + (size_t)(cbase + r0) * 256 + k0 + kc * 8);
            rb1 = *(const short8v*)(cb1 + (size_t)(cbase + r1) * 256 + k0 + kc * 8);
        }
        __syncthreads();

        short8v af[4], bfv[4];
        #pragma unroll
        for (int fi = 0; fi < 4; ++fi) {
            int row = wr * 64 + fi * 16 + lr;
            int slot = lk ^ ((row >> 1) & 3);
            af[fi] = *(const short8v*)(Asm + row * 64 + slot * 16);
        }
        #pragma unroll
        for (int fj = 0; fj < 4; ++fj) {
            int row = wc * 64 + fj * 16 + lr;
            int slot = lk ^ ((row >> 1) & 3);
            bfv[fj] = *(const short8v*)(Bsm + row * 64 + slot * 16);
        }
        #pragma unroll
        for (int fi = 0; fi < 4; ++fi)
            #pragma unroll
            for (int fj = 0; fj < 4; ++fj)
                acc[fi][fj] = __builtin_amdgcn_mfma_f32_16x16x32_bf16(
                    af[fi], bfv[fj], acc[fi][fj], 0, 0, 0);
    }

    __syncthreads();   // done with staging region; reuse as entries

    // per-lane per-row top2 over this wave's 64-code span
    #pragma unroll
    for (int fi = 0; fi < 4; ++fi) {
        #pragma unroll
        for (int r = 0; r < 4; ++r) {
            int q = wr * 64 + fi * 16 + lk * 4 + r;
            float m1 = 3e38f, m2 = 3e38f; uint i1 = 0;
            #pragma unroll
            for (int fj = 0; fj < 4; ++fj) {
                int c = wc * 64 + fj * 16 + lr;
                float s = fmaf(-2.0f, acc[fi][fj][r], csq_lds[c]);
                uint gidx = (uint)(cbase + c);
                if (s < m1) { m2 = m1; m1 = s; i1 = gidx; }
                else if (s < m2) { m2 = s; }
            }
            int col = wc * 16 + lr;
            emin1[q * 33 + col] = m1;
            emin2[q * 33 + col] = m2;
            eidx [q * 33 + col] = i1;
        }
    }
    __syncthreads();

    // pass2: merge 32 entries per query -> per-(query, N-tile) top2
    {
        int q = t >> 1, h = t & 1;
        float m1 = 3e38f, m2 = 3e38f; uint i1 = 0;
        #pragma unroll 4
        for (int j = 0; j < 16; ++j) {
            int col = h * 16 + j;
            float a1 = emin1[q * 33 + col];
            float a2 = emin2[q * 33 + col];
            uint  ai = eidx [q * 33 + col];
            if (a1 < m1) { m2 = fminf(m1, a2); m1 = a1; i1 = ai; }
            else         { m2 = fminf(m2, a1); }
        }
        float o1 = __shfl_xor(m1, 1);
        float o2 = __shfl_xor(m2, 1);
        uint  oi = __shfl_xor(i1, 1);
        if (o1 < m1) { m2 = fminf(m1, o2); m1 = o1; i1 = oi; }
        else         { m2 = fminf(m2, o1); }
        if (h == 0) {
            int qg = qbase + q;
            pm1[qg * 16 + nt] = m1;
            pm2[qg * 16 + nt] = m2;
            pidxg[qg * 16 + nt] = i1;
        }
    }
}

// ---------------- merge tiles, flag near-ties ----------------
__global__ __launch_bounds__(256)
void vq_merge(const float* __restrict__ pm1, const float* __restrict__ pm2,
              const uint* __restrict__ pidxg, int* __restrict__ idxout,
              int* __restrict__ flaglist, int* __restrict__ count) {
    int q = blockIdx.x * 256 + threadIdx.x;
    float g1 = 3e38f, g2 = 3e38f; uint gi = 0;
    #pragma unroll 4
    for (int tl = 0; tl < 16; ++tl) {
        float a1 = pm1[q * 16 + tl];
        float a2 = pm2[q * 16 + tl];
        uint  ai = pidxg[q * 16 + tl];
        if (a1 < g1) { g2 = fminf(g1, a2); g1 = a1; gi = ai; }
        else         { g2 = fminf(g2, a1); }
    }
    idxout[q] = (int)gi;
    if (g2 - g1 < TAU) {
        int p = atomicAdd(count, 1);
        flaglist[p] = q;
    }
}

// ---------------- stage 2: exact fp64 + fp32-replay for flagged ----------------
__global__ __launch_bounds__(256)
void vq_exact(const float* __restrict__ emb, const float* __restrict__ cb,
              const float* __restrict__ csq, const int* __restrict__ flaglist,
              const int* __restrict__ count, int* __restrict__ idxout) {
    __shared__ float xrow[16 * 260];
    __shared__ float cbt[32 * 260];
    __shared__ float xs_l[16];
    __shared__ float csq_t[32];

    int cnt = *count;
    int base = blockIdx.x * 16;
    if (base >= cnt) return;
    int nq = min(16, cnt - base);

    int t = threadIdx.x;
    int qi = t >> 4, ks = t & 15;
    int q = 0;
    if (qi < nq) {
        q = flaglist[base + qi];
        int b = q >> 10, hw = q & 1023;
        double xp = 0.0;
        #pragma unroll 4
        for (int j = 0; j < 16; ++j) {
            int e = ks * 16 + j;
            float v = emb[((b * 256 + e) << 10) + hw];
            xrow[qi * 260 + e] = v;
            xp = fma((double)v, (double)v, xp);
        }
        for (int m = 1; m < 16; m <<= 1) xp += __shfl_xor(xp, m);
        if (ks == 0) xs_l[qi] = (float)xp;
    }
    __syncthreads();
    float xs = (qi < nq) ? xs_l[qi] : 0.f;

    float best_d = 3e38f; int best_i = 0;
    for (int tile = 0; tile < 64; ++tile) {
        __syncthreads();
        #pragma unroll
        for (int j = 0; j < 8; ++j) {
            int c = j * 256 + t;               // float4 chunk id
            int row = c >> 6, col4 = c & 63;
            float4 f4 = ((const float4*)cb)[(tile * 32 + row) * 64 + col4];
            float* dst = &cbt[row * 260 + col4 * 4];
            dst[0] = f4.x; dst[1] = f4.y; dst[2] = f4.z; dst[3] = f4.w;
        }
        if (t < 32) csq_t[t] = csq[tile * 32 + t];
        __syncthreads();
        if (qi < nq) {
            #pragma unroll
            for (int half = 0; half < 2; ++half) {
                int cc = ks + half * 16;
                double a0 = 0.0, a1 = 0.0;
                const float* xr = &xrow[qi * 260];
                const float* cr = &cbt[cc * 260];
                #pragma unroll 8
                for (int e4 = 0; e4 < 64; ++e4) {
                    float4 x4 = *(const float4*)(xr + e4 * 4);
                    float4 c4 = *(const float4*)(cr + e4 * 4);
                    a0 = fma((double)x4.x, (double)c4.x, a0);
                    a1 = fma((double)x4.y, (double)c4.y, a1);
                    a0 = fma((double)x4.z, (double)c4.z, a0);
                    a1 = fma((double)x4.w, (double)c4.w, a1);
                }
                float g = (float)(a0 + a1);     // fl32(exact dot)
                float G = g + g;
                float tq = xs - G;              // fp32 rounding replay
                float d = tq + csq_t[cc];
                int gidx = tile * 32 + cc;
                if (d < best_d) { best_d = d; best_i = gidx; }
            }
        }
    }
    for (int m = 1; m < 16; m <<= 1) {
        float od = __shfl_xor(best_d, m);
        int   oi = __shfl_xor(best_i, m);
        if (od < best_d || (od == best_d && oi < best_i)) {
            best_d = od; best_i = oi;
        }
    }
    if (qi < nq && ks == 0) idxout[q] = best_i;
}

// ---------------- gather ----------------
__global__ __launch_bounds__(256)
void vq_gather(const float* __restrict__ cb, const int* __restrict__ idxout,
               float* __restrict__ out) {
    int t = threadIdx.x;
    int b = blockIdx.x >> 2, hq = blockIdx.x & 3;
    int n = b * HW + hq * 256 + t;
    int bi = idxout[n];
    const float4* row = (const float4*)(cb + (size_t)bi * 256);
    float* outB = out + (size_t)b * 256 * HW + hq * 256 + t;
    #pragma unroll 4
    for (int e4 = 0; e4 < 64; ++e4) {
        float4 c = row[e4];
        outB[(size_t)(e4 * 4 + 0) * HW] = c.x;
        outB[(size_t)(e4 * 4 + 1) * HW] = c.y;
        outB[(size_t)(e4 * 4 + 2) * HW] = c.z;
        outB[(size_t)(e4 * 4 + 3) * HW] = c.w;
    }
}

extern "C" void kernel_launch(void* const* d_in, const int* in_sizes, int n_in,
                              void* d_out, int out_size, void* d_ws, size_t ws_size,
                              hipStream_t stream) {
    const float* emb = (const float*)d_in[0];   // [32, 256, 32, 32] fp32
    const float* cb  = (const float*)d_in[1];   // [2048, 256] fp32
    float* out = (float*)d_out;

    char* ws = (char*)d_ws;
    ushort* xb    = (ushort*)ws;                        // 16 MB
    ushort* cb1   = (ushort*)(ws + 16777216);           // 1 MB
    float*  csq   = (float*) (ws + 17825792);           // 8 KB
    float*  pm1   = (float*) (ws + 17833984);           // 2 MB
    float*  pm2   = (float*) (ws + 19931136);           // 2 MB
    uint*   pidxg = (uint*)  (ws + 22028288);           // 2 MB
    int* idxout   = (int*)   (ws + 24125440);           // 128 KB
    int* flaglist = (int*)   (ws + 24256512);           // 128 KB
    int* count    = (int*)   (ws + 24387584);           // 4 B

    hipMemsetAsync(count, 0, 4, stream);
    prep_cb <<<512,  256, 0, stream>>>(cb, cb1, csq);
    prep_x  <<<2048, 256, 0, stream>>>(emb, xb);
    vq_gemm <<<4096, 256, 0, stream>>>(xb, cb1, csq, pm1, pm2, pidxg);
    vq_merge<<<128,  256, 0, stream>>>(pm1, pm2, pidxg, idxout, flaglist, count);
    vq_exact<<<2048, 256, 0, stream>>>(emb, cb, csq, flaglist, count, idxout);
    vq_gather<<<128, 256, 0, stream>>>(cb, idxout, out);
}

// Round 4
// 244.541 us; speedup vs baseline: 4.0943x; 1.7356x over previous
//
#include <hip/hip_runtime.h>

typedef unsigned int uint;
typedef unsigned short ushort;
typedef unsigned long long u64;
typedef __attribute__((ext_vector_type(8))) short short8v;   // 8 bf16 in 4 VGPRs
typedef __attribute__((ext_vector_type(4))) float float4v;

#define NQ    32768
#define KALL  2048
#define E_DIM 256
#define HW    1024
#define TAU   2.5e-4f
#define NB    64      // exact-stage blocks per tile
#define QPB   32      // queries per exact-stage block

static __device__ __forceinline__ ushort f2bf(float f) {
    uint u = __float_as_uint(f);
    uint r = (u + 0x7fffu + ((u >> 16) & 1u)) >> 16;   // RNE, no NaN inputs
    return (ushort)r;
}

static __device__ __forceinline__ u64 u64min(u64 a, u64 b) { return a < b ? a : b; }

// ---------------- prep: codebook -> bf16 + fp32 csq ----------------
__global__ __launch_bounds__(256)
void prep_cb(const float* __restrict__ cb, ushort* __restrict__ cb1,
             float* __restrict__ csq) {
    int row  = blockIdx.x * 4 + (threadIdx.x >> 6);
    int lane = threadIdx.x & 63;
    float4 v = ((const float4*)cb)[row * 64 + lane];
    double s = (double)v.x * v.x + (double)v.y * v.y +
               (double)v.z * v.z + (double)v.w * v.w;
    for (int m = 1; m < 64; m <<= 1) s += __shfl_xor(s, m);
    if (lane == 0) csq[row] = (float)s;    // fl32(exact ||c||^2)
    uint u0 = (uint)f2bf(v.x) | ((uint)f2bf(v.y) << 16);
    uint u1 = (uint)f2bf(v.z) | ((uint)f2bf(v.w) << 16);
    ((uint2*)cb1)[row * 64 + lane] = make_uint2(u0, u1);
}

// ---------------- prep: emb [B][E][HW] -> xb bf16 [N][E] ----------------
__global__ __launch_bounds__(256)
void prep_x(const float* __restrict__ emb, ushort* __restrict__ xb) {
    __shared__ float ldsf[64 * 65];
    int blk = blockIdx.x;
    int img = blk >> 6;
    int tile = blk & 63;
    int e0  = (tile >> 4) * 64;
    int hw0 = (tile & 15) * 64;
    int t = threadIdx.x;
    int rr = t >> 6;          // 0..3
    int c  = t & 63;
    #pragma unroll 4
    for (int i = 0; i < 16; ++i) {
        int r = i * 4 + rr;
        float v = emb[((img * 256 + e0 + r) << 10) + hw0 + c];
        ldsf[c * 65 + r] = v;              // transpose into LDS, conflict-free
    }
    __syncthreads();
    int hr = t >> 5;          // 0..7
    int ep = t & 31;
    #pragma unroll 4
    for (int i = 0; i < 8; ++i) {
        int hwr = i * 8 + hr;
        float v0 = ldsf[hwr * 65 + ep * 2];
        float v1 = ldsf[hwr * 65 + ep * 2 + 1];
        uint u = (uint)f2bf(v0) | ((uint)f2bf(v1) << 16);
        ((uint*)xb)[((img * 1024 + hw0 + hwr) << 7) + (e0 >> 1) + ep] = u;
    }
}

// ---------------- stage 1: bf16 MFMA GEMM + per-tile top2 ----------------
__global__ __launch_bounds__(256, 2)
void vq_gemm(const ushort* __restrict__ xb, const ushort* __restrict__ cb1,
             const float* __restrict__ csq,
             float* __restrict__ pm1, float* __restrict__ pm2,
             uint* __restrict__ pidxg) {
    __shared__ char smem[50688];          // union: staging (16KB) / entries (49.5KB)
    __shared__ float csq_lds[128];
    char* Asm = smem;
    char* Bsm = smem + 8192;
    float* emin1 = (float*)smem;                 // [128][33]
    float* emin2 = (float*)(smem + 16896);
    uint*  eidx  = (uint*)(smem + 33792);

    int t = threadIdx.x;
    int bi = blockIdx.x;
    int mt = bi >> 4;            // 256 M-tiles
    int nt = bi & 15;            // 16 N-tiles
    int qbase = mt * 128;
    int cbase = nt * 128;

    if (t < 128) csq_lds[t] = csq[cbase + t];

    int wid = t >> 6, lane = t & 63;
    int wr = wid >> 1, wc = wid & 1;
    int lr = lane & 15, lk = lane >> 4;

    float4v acc[4][4];
    #pragma unroll
    for (int i = 0; i < 4; ++i)
        #pragma unroll
        for (int j = 0; j < 4; ++j)
            acc[i][j] = (float4v){0.f, 0.f, 0.f, 0.f};

    // staging map: thread covers rows r0=t>>2 and r1=64+(t>>2), k-chunk kc=t&3
    int r0 = t >> 2, r1 = 64 + (t >> 2), kc = t & 3;
    int dst0 = r0 * 64 + ((kc ^ ((r0 >> 1) & 3)) << 4);   // XOR slot swizzle
    int dst1 = r1 * 64 + ((kc ^ ((r1 >> 1) & 3)) << 4);

    short8v ra0, ra1, rb0, rb1;
    {
        int k0 = 0;
        ra0 = *(const short8v*)(xb  + (size_t)(qbase + r0) * 256 + k0 + kc * 8);
        ra1 = *(const short8v*)(xb  + (size_t)(qbase + r1) * 256 + k0 + kc * 8);
        rb0 = *(const short8v*)(cb1 + (size_t)(cbase + r0) * 256 + k0 + kc * 8);
        rb1 = *(const short8v*)(cb1 + (size_t)(cbase + r1) * 256 + k0 + kc * 8);
    }

    for (int kt = 0; kt < 8; ++kt) {
        __syncthreads();
        *(short8v*)(Asm + dst0) = ra0;
        *(short8v*)(Asm + dst1) = ra1;
        *(short8v*)(Bsm + dst0) = rb0;
        *(short8v*)(Bsm + dst1) = rb1;
        if (kt < 7) {                       // prefetch next K-step under compute
            int k0 = (kt + 1) * 32;
            ra0 = *(const short8v*)(xb  + (size_t)(qbase + r0) * 256 + k0 + kc * 8);
            ra1 = *(const short8v*)(xb  + (size_t)(qbase + r1) * 256 + k0 + kc * 8);
            rb0 = *(const short8v*)(cb1 + (size_t)(cbase + r0) * 256 + k0 + kc * 8);
            rb1 = *(const short8v*)(cb1 + (size_t)(cbase + r1) * 256 + k0 + kc * 8);
        }
        __syncthreads();

        short8v af[4], bfv[4];
        #pragma unroll
        for (int fi = 0; fi < 4; ++fi) {
            int row = wr * 64 + fi * 16 + lr;
            int slot = lk ^ ((row >> 1) & 3);
            af[fi] = *(const short8v*)(Asm + row * 64 + slot * 16);
        }
        #pragma unroll
        for (int fj = 0; fj < 4; ++fj) {
            int row = wc * 64 + fj * 16 + lr;
            int slot = lk ^ ((row >> 1) & 3);
            bfv[fj] = *(const short8v*)(Bsm + row * 64 + slot * 16);
        }
        #pragma unroll
        for (int fi = 0; fi < 4; ++fi)
            #pragma unroll
            for (int fj = 0; fj < 4; ++fj)
                acc[fi][fj] = __builtin_amdgcn_mfma_f32_16x16x32_bf16(
                    af[fi], bfv[fj], acc[fi][fj], 0, 0, 0);
    }

    __syncthreads();   // done with staging region; reuse as entries

    // per-lane per-row top2 over this wave's 64-code span
    #pragma unroll
    for (int fi = 0; fi < 4; ++fi) {
        #pragma unroll
        for (int r = 0; r < 4; ++r) {
            int q = wr * 64 + fi * 16 + lk * 4 + r;
            float m1 = 3e38f, m2 = 3e38f; uint i1 = 0;
            #pragma unroll
            for (int fj = 0; fj < 4; ++fj) {
                int c = wc * 64 + fj * 16 + lr;
                float s = fmaf(-2.0f, acc[fi][fj][r], csq_lds[c]);
                uint gidx = (uint)(cbase + c);
                if (s < m1) { m2 = m1; m1 = s; i1 = gidx; }
                else if (s < m2) { m2 = s; }
            }
            int col = wc * 16 + lr;
            emin1[q * 33 + col] = m1;
            emin2[q * 33 + col] = m2;
            eidx [q * 33 + col] = i1;
        }
    }
    __syncthreads();

    // pass2: merge 32 entries per query -> per-(query, N-tile) top2
    {
        int q = t >> 1, h = t & 1;
        float m1 = 3e38f, m2 = 3e38f; uint i1 = 0;
        #pragma unroll 4
        for (int j = 0; j < 16; ++j) {
            int col = h * 16 + j;
            float a1 = emin1[q * 33 + col];
            float a2 = emin2[q * 33 + col];
            uint  ai = eidx [q * 33 + col];
            if (a1 < m1) { m2 = fminf(m1, a2); m1 = a1; i1 = ai; }
            else         { m2 = fminf(m2, a1); }
        }
        float o1 = __shfl_xor(m1, 1);
        float o2 = __shfl_xor(m2, 1);
        uint  oi = __shfl_xor(i1, 1);
        if (o1 < m1) { m2 = fminf(m1, o2); m1 = o1; i1 = oi; }
        else         { m2 = fminf(m2, o1); }
        if (h == 0) {
            int qg = qbase + q;
            pm1[qg * 16 + nt] = m1;
            pm2[qg * 16 + nt] = m2;
            pidxg[qg * 16 + nt] = i1;
        }
    }
}

// ---------------- merge tiles, flag near-ties into per-tile buckets ----------------
__global__ __launch_bounds__(256)
void vq_merge(const float* __restrict__ pm1, const float* __restrict__ pm2,
              const uint* __restrict__ pidxg, int* __restrict__ idxout,
              int* __restrict__ bucket, int* __restrict__ cnt) {
    int q = blockIdx.x * 256 + threadIdx.x;
    float g1 = 3e38f, g2 = 3e38f; uint gi = 0;
    float m1v[16];
    #pragma unroll
    for (int tl = 0; tl < 16; ++tl) {
        float a1 = pm1[q * 16 + tl];
        float a2 = pm2[q * 16 + tl];
        uint  ai = pidxg[q * 16 + tl];
        m1v[tl] = a1;
        if (a1 < g1) { g2 = fminf(g1, a2); g1 = a1; gi = ai; }
        else         { g2 = fminf(g2, a1); }
    }
    idxout[q] = (int)gi;
    if (g2 - g1 < TAU) {
        float lim = g1 + TAU;
        #pragma unroll
        for (int tl = 0; tl < 16; ++tl) {
            if (m1v[tl] < lim) {           // candidate tile: could hold the true winner
                int p = atomicAdd(&cnt[tl], 1);
                bucket[tl * NQ + p] = q;
            }
        }
    }
}

// ---------------- stage 2: exact fp64 + fp32-replay, bucketed per tile ----------------
__global__ __launch_bounds__(256)
void vq_exact2(const float* __restrict__ emb, const float* __restrict__ cb,
               const float* __restrict__ csq, const int* __restrict__ bucket,
               const int* __restrict__ cnt, u64* __restrict__ best64) {
    __shared__ float xrow[QPB * 260];    // 33.3 KB
    __shared__ float cbt[16 * 260];      // 16.6 KB
    __shared__ int   qids[QPB];
    __shared__ float xsl[QPB];
    __shared__ float csq_l[128];

    const int tile = blockIdx.x >> 6;    // 0..15
    const int slot = blockIdx.x & 63;    // 0..NB-1
    const int t  = threadIdx.x;
    const int cn = cnt[tile];
    const int qi = t >> 3, es = t & 7;   // 32 queries x 8 lanes

    for (int base = slot * QPB; base < cn; base += NB * QPB) {
        const int nq = min(QPB, cn - base);
        __syncthreads();                         // protect qids/xrow reuse
        if (t < nq)  qids[t]  = bucket[tile * NQ + base + t];
        if (t < 128) csq_l[t] = csq[tile * 128 + t];
        __syncthreads();

        // load 32 query rows (scattered 4B, L3-resident) + exact ||x||^2
        double xp = 0.0;
        if (qi < nq) {
            const int q  = qids[qi];
            const int b  = q >> 10, hw = q & 1023;
            const float* __restrict__ ep = emb + ((size_t)b << 18) + hw;
            #pragma unroll 8
            for (int j = 0; j < 32; ++j) {
                int e = j * 8 + es;              // interleave: kills LDS write conflicts
                float v = ep[(size_t)e << 10];
                xrow[qi * 260 + e] = v;
                xp = fma((double)v, (double)v, xp);
            }
        }
        xp += __shfl_xor(xp, 1);
        xp += __shfl_xor(xp, 2);
        xp += __shfl_xor(xp, 4);
        if (qi < nq && es == 0) xsl[qi] = (float)xp;

        u64 pk = ~0ULL;
        for (int ch = 0; ch < 8; ++ch) {         // 8 chunks of 16 codebook rows
            __syncthreads();                     // protect cbt
            {
                const float4* __restrict__ csrc =
                    (const float4*)(cb + ((size_t)tile * 128 + ch * 16) * 256);
                #pragma unroll
                for (int j = 0; j < 4; ++j) {
                    int idx = j * 256 + t;
                    int row = idx >> 6, c4 = idx & 63;
                    float4 v = csrc[idx];        // coalesced
                    *(float4*)&cbt[row * 260 + c4 * 4] = v;
                }
            }
            __syncthreads();
            if (qi < nq) {
                const float xs = xsl[qi];
                #pragma unroll
                for (int h = 0; h < 2; ++h) {
                    const int cc = es + h * 8;
                    double a0 = 0.0, a1 = 0.0;
                    const float* __restrict__ xr = &xrow[qi * 260];
                    const float* __restrict__ cr = &cbt[cc * 260];
                    #pragma unroll 8
                    for (int e4 = 0; e4 < 64; ++e4) {
                        float4 x4 = *(const float4*)(xr + e4 * 4);
                        float4 c4 = *(const float4*)(cr + e4 * 4);
                        a0 = fma((double)x4.x, (double)c4.x, a0);
                        a1 = fma((double)x4.y, (double)c4.y, a1);
                        a0 = fma((double)x4.z, (double)c4.z, a0);
                        a1 = fma((double)x4.w, (double)c4.w, a1);
                    }
                    float g = (float)(a0 + a1);  // fl32(exact dot)
                    float G = g + g;
                    float d = (xs - G) + csq_l[ch * 16 + cc];   // fp32 rounding replay
                    uint gidx = (uint)(tile * 128 + ch * 16 + cc);
                    u64 cand = ((u64)__float_as_uint(d) << 32) | gidx;
                    pk = u64min(pk, cand);
                }
            }
        }
        pk = u64min(pk, __shfl_xor(pk, 1));
        pk = u64min(pk, __shfl_xor(pk, 2));
        pk = u64min(pk, __shfl_xor(pk, 4));
        if (qi < nq && es == 0)
            atomicMin(&best64[qids[qi]], pk);    // (d, idx) lexicographic: numpy tiebreak
    }
}

// ---------------- gather ----------------
__global__ __launch_bounds__(256)
void vq_gather(const float* __restrict__ cb, const int* __restrict__ idxout,
               const u64* __restrict__ best64, float* __restrict__ out) {
    int t = threadIdx.x;
    int b = blockIdx.x >> 2, hq = blockIdx.x & 3;
    int n = b * HW + hq * 256 + t;
    u64 pk = best64[n];
    int bi = (pk != ~0ULL) ? (int)(pk & 0xffffffffu) : idxout[n];
    const float4* row = (const float4*)(cb + (size_t)bi * 256);
    float* outB = out + (size_t)b * 256 * HW + hq * 256 + t;
    #pragma unroll 4
    for (int e4 = 0; e4 < 64; ++e4) {
        float4 c = row[e4];
        outB[(size_t)(e4 * 4 + 0) * HW] = c.x;
        outB[(size_t)(e4 * 4 + 1) * HW] = c.y;
        outB[(size_t)(e4 * 4 + 2) * HW] = c.z;
        outB[(size_t)(e4 * 4 + 3) * HW] = c.w;
    }
}

extern "C" void kernel_launch(void* const* d_in, const int* in_sizes, int n_in,
                              void* d_out, int out_size, void* d_ws, size_t ws_size,
                              hipStream_t stream) {
    const float* emb = (const float*)d_in[0];   // [32, 256, 32, 32] fp32
    const float* cb  = (const float*)d_in[1];   // [2048, 256] fp32
    float* out = (float*)d_out;

    char* ws = (char*)d_ws;
    ushort* xb     = (ushort*)ws;                        // 16 MB
    ushort* cb1    = (ushort*)(ws + 16777216);           // 1 MB
    float*  csq    = (float*) (ws + 17825792);           // 8 KB
    float*  pm1    = (float*) (ws + 17833984);           // 2 MB
    float*  pm2    = (float*) (ws + 19931136);           // 2 MB
    uint*   pidxg  = (uint*)  (ws + 22028288);           // 2 MB
    int*    idxout = (int*)   (ws + 24125440);           // 128 KB
    int*    bucket = (int*)   (ws + 24256512);           // 2 MB (16 x 32768)
    int*    cnt    = (int*)   (ws + 26353664);           // 64 B (pad 256)
    u64*    best64 = (u64*)   (ws + 26353920);           // 256 KB

    hipMemsetAsync(cnt, 0, 64, stream);
    hipMemsetAsync(best64, 0xFF, NQ * sizeof(u64), stream);
    prep_cb  <<<512,     256, 0, stream>>>(cb, cb1, csq);
    prep_x   <<<2048,    256, 0, stream>>>(emb, xb);
    vq_gemm  <<<4096,    256, 0, stream>>>(xb, cb1, csq, pm1, pm2, pidxg);
    vq_merge <<<128,     256, 0, stream>>>(pm1, pm2, pidxg, idxout, bucket, cnt);
    vq_exact2<<<16 * NB, 256, 0, stream>>>(emb, cb, csq, bucket, cnt, best64);
    vq_gather<<<128,     256, 0, stream>>>(cb, idxout, best64, out);
}